// Round 6
// baseline (49.453 us; speedup 1.0000x reference)
//
#include <hip/hip_runtime.h>
#include <math.h>

#define BB 512
#define DD 256
#define TMARGIN 0.2f
#define NBLK 256          // 2 anchors per block
#define NTHR 512          // thread t owns column/negative j = t
#define DT 32             // d-tile width (floats)
#define NTILE (DD / DT)   // 8 tiles
#define F4_PER_ROW_TILE (DT / 4)   // 8 float4 per row per tile

// ---------------- Kernel 1: per-block triplet partials (2 anchors/block) ----------------
// grid 256 x 512. Phase 1 stages X into LDS coalesced (XOR-swizzled b128), software-pipelined.
__global__ void __launch_bounds__(NTHR)
tl_part(const float* __restrict__ X,
        const int* __restrict__ labels,
        float* __restrict__ psum,
        unsigned int* __restrict__ pcount) {
    __shared__ float4 tileS[BB * F4_PER_ROW_TILE];   // 64 KB: [row][slot], slot = dd4 ^ (row&7)
    __shared__ float  drowL[2][520];    // [anchor][col]; slots 512.. = -1e30 sentinel
    __shared__ int    labL[BB];
    __shared__ int    plist[2][520];
    __shared__ int    pcnt[2];
    __shared__ float  nsh[2];           // anchor squared norms
    __shared__ float  partf[8];

    const int t   = threadIdx.x;        // 0..511 == column j
    const int ia0 = blockIdx.x * 2;
    const int ia1 = ia0 + 1;

    labL[t] = labels[t];
    if (t < 2) pcnt[t] = 0;
    if (t < 16) drowL[t >> 3][512 + (t & 7)] = -1e30f;   // sentinel pads
    __syncthreads();

    // ---- build positive lists (LDS atomics) ----
    {
        const int l0 = labL[ia0], l1 = labL[ia1];
        if (labL[t] == l0 && t != ia0) plist[0][atomicAdd(&pcnt[0], 1)] = t;
        if (labL[t] == l1 && t != ia1) plist[1][atomicAdd(&pcnt[1], 1)] = t;
    }

    // ---- phase 1: LDS-staged, coalesced, pipelined ----
    // Per-thread staging geometry (constant across tiles):
    //   r in [0,8): row j_r = r*64 + (t>>3), f4-column dd4 = t&7, swizzle slot s = dd4 ^ (j_r&7)
    const int   g      = t >> 3;                 // row-group 0..63
    const int   dd4    = t & 7;
    const int   sslot  = dd4 ^ (g & 7);          // (j_r & 7) == (g & 7) since r*64 % 8 == 0
    const float4* X4   = (const float4*)X;       // row stride 64 float4
    const float4* A4   = X4 + (size_t)ia0 * 64;  // block-uniform -> scalar loads
    const float4* B4   = X4 + (size_t)ia1 * 64;

    float4 rg[8];
    #pragma unroll
    for (int r = 0; r < 8; ++r)
        rg[r] = X4[(size_t)(r * 64 + g) * 64 + dd4];          // tile 0

    float a0 = 0.f, a1 = 0.f, nn = 0.f;
    for (int ti = 0; ti < NTILE; ++ti) {
        __syncthreads();      // previous tile's compute done (iter 0: plist atomics done)
        #pragma unroll
        for (int r = 0; r < 8; ++r)
            tileS[(r * 64 + g) * F4_PER_ROW_TILE + sslot] = rg[r];
        if (ti < NTILE - 1) {
            #pragma unroll
            for (int r = 0; r < 8; ++r)
                rg[r] = X4[(size_t)(r * 64 + g) * 64 + (ti + 1) * 8 + dd4];  // prefetch next tile
        }
        __syncthreads();      // tile ready
        #pragma unroll
        for (int k = 0; k < 8; ++k) {
            const float4 v = tileS[t * F4_PER_ROW_TILE + (k ^ (t & 7))];  // row t, d-chunk k
            const float4 u = A4[ti * 8 + k];
            const float4 w = B4[ti * 8 + k];
            a0 += u.x * v.x + u.y * v.y + u.z * v.z + u.w * v.w;
            a1 += w.x * v.x + w.y * v.y + w.z * v.z + w.w * v.w;
            nn += v.x * v.x + v.y * v.y + v.z * v.z + v.w * v.w;
        }
    }

    if (t == ia0) nsh[0] = nn;          // anchor norms from diagonal threads
    if (t == ia1) nsh[1] = nn;
    __syncthreads();

    // ---- distances for column t vs both anchors ----
    float dk0, dk1;
    {
        const float s0 = nsh[0] + nn - 2.0f * a0;
        const float s1 = nsh[1] + nn - 2.0f * a1;
        dk0 = (s0 > 0.0f) ? sqrtf(s0) : 0.0f;
        dk1 = (s1 > 0.0f) ? sqrtf(s1) : 0.0f;
        drowL[0][t] = dk0;
        drowL[1][t] = dk1;
    }
    // pad positive lists to multiple of 8 with sentinel index 512
    if (t < 8) {
        int np = pcnt[0], pad = ((np + 7) & ~7) - np;
        if (t < pad) plist[0][np + t] = 512;
    } else if (t < 16) {
        int q = t - 8;
        int np = pcnt[1], pad = ((np + 7) & ~7) - np;
        if (q < pad) plist[1][np + q] = 512;
    }
    __syncthreads();

    // ---- phase 2: thread owns negative k = t for both anchors ----
    float lsum = 0.0f;
    #pragma unroll
    for (int a = 0; a < 2; ++a) {
        const int li   = labL[ia0 + a];
        const bool neg = (labL[t] != li);
        const float dk = (a == 0) ? dk0 : dk1;
        const int npp  = (pcnt[a] + 7) & ~7;
        float s = 0.0f;
        for (int p = 0; p < npp; p += 8) {
            float dj0 = drowL[a][plist[a][p + 0]];   // uniform -> LDS broadcast
            float dj1 = drowL[a][plist[a][p + 1]];
            float dj2 = drowL[a][plist[a][p + 2]];
            float dj3 = drowL[a][plist[a][p + 3]];
            float dj4 = drowL[a][plist[a][p + 4]];
            float dj5 = drowL[a][plist[a][p + 5]];
            float dj6 = drowL[a][plist[a][p + 6]];
            float dj7 = drowL[a][plist[a][p + 7]];
            s += fmaxf(dj0 - dk + TMARGIN, 0.0f);
            s += fmaxf(dj1 - dk + TMARGIN, 0.0f);
            s += fmaxf(dj2 - dk + TMARGIN, 0.0f);
            s += fmaxf(dj3 - dk + TMARGIN, 0.0f);
            s += fmaxf(dj4 - dk + TMARGIN, 0.0f);
            s += fmaxf(dj5 - dk + TMARGIN, 0.0f);
            s += fmaxf(dj6 - dk + TMARGIN, 0.0f);
            s += fmaxf(dj7 - dk + TMARGIN, 0.0f);
        }
        if (neg) lsum += s;
    }

    // ---- block reduction, write this block's partial to its own slot ----
    #pragma unroll
    for (int o = 32; o > 0; o >>= 1) lsum += __shfl_xor(lsum, o, 64);
    if ((t & 63) == 0) partf[t >> 6] = lsum;
    __syncthreads();
    if (t == 0) {
        float bsum = 0.0f;
        #pragma unroll
        for (int w = 0; w < 8; ++w) bsum += partf[w];
        unsigned int bcnt = 0;
        #pragma unroll
        for (int a = 0; a < 2; ++a) {
            unsigned int np = (unsigned int)pcnt[a];
            bcnt += np * (unsigned int)(BB - 1 - np);
        }
        psum[blockIdx.x]   = bsum;     // plain stores; kernel-boundary coherence
        pcount[blockIdx.x] = bcnt;
    }
}

// ---------------- Kernel 2: reduce 256 partials, finalize ----------------
// 1 block x 256 threads
__global__ void tl_reduce(const float* __restrict__ psum,
                          const unsigned int* __restrict__ pcount,
                          float* __restrict__ out) {
    __shared__ float        sf[4];
    __shared__ unsigned int sc[4];
    const int t = threadIdx.x;
    float        s = psum[t];
    unsigned int c = pcount[t];
    #pragma unroll
    for (int o = 32; o > 0; o >>= 1) {
        s += __shfl_xor(s, o, 64);
        c += __shfl_xor(c, o, 64);
    }
    if ((t & 63) == 0) { sf[t >> 6] = s; sc[t >> 6] = c; }
    __syncthreads();
    if (t == 0) {
        float        tt = sf[0] + sf[1] + sf[2] + sf[3];
        unsigned int cc = sc[0] + sc[1] + sc[2] + sc[3];
        out[0] = (cc > 0u) ? (tt / (float)cc) : 0.0f;
    }
}

extern "C" void kernel_launch(void* const* d_in, const int* in_sizes, int n_in,
                              void* d_out, int out_size, void* d_ws, size_t ws_size,
                              hipStream_t stream) {
    const float* X      = (const float*)d_in[0];   // [512,256] f32
    const int*   labels = (const int*)d_in[1];     // [512] int

    float*        psum   = (float*)d_ws;                          // 256 f32, all rewritten each call
    unsigned int* pcount = (unsigned int*)((char*)d_ws + 1024);   // 256 u32, all rewritten each call

    // NOTE: no hipMemsetAsync — every ws slot consumed is produced this call.
    tl_part<<<NBLK, NTHR, 0, stream>>>(X, labels, psum, pcount);
    tl_reduce<<<1, 256, 0, stream>>>(psum, pcount, (float*)d_out);
}

// Round 7
// 23.141 us; speedup vs baseline: 2.1370x; 2.1370x over previous
//
#include <hip/hip_runtime.h>
#include <math.h>

#define BB 512
#define DD 256
#define TMARGIN 0.2f
#define NBLK 256          // 2 anchors per block
#define NTHR 512          // thread t owns column/negative j = t

// ---------------- Kernel 1: per-block triplet partials (2 anchors/block) ----------------
// grid 256 x 512. Phase 1: 8-lane-cooperative coalesced row reads + wave-transpose gather.
__global__ void __launch_bounds__(NTHR, 2)
tl_part(const float* __restrict__ X,
        const int* __restrict__ labels,
        float* __restrict__ psum,
        unsigned int* __restrict__ pcount) {
    __shared__ float drowL[2][520];     // [anchor][col]; slots 512.. = -1e30 sentinel
    __shared__ int   labL[BB];
    __shared__ int   plist[2][520];
    __shared__ int   pcnt[2];
    __shared__ float nsh[2];            // anchor squared norms
    __shared__ float partf[8];

    const int t   = threadIdx.x;        // 0..511 == row/column j it owns
    const int ia0 = blockIdx.x * 2;
    const int ia1 = ia0 + 1;

    labL[t] = labels[t];
    if (t < 2) pcnt[t] = 0;
    if (t < 16) drowL[t >> 3][512 + (t & 7)] = -1e30f;   // sentinel pads
    __syncthreads();

    // ---- build positive lists (LDS atomics) ----
    {
        const int l0 = labL[ia0], l1 = labL[ia1];
        if (labL[t] == l0 && t != ia0) plist[0][atomicAdd(&pcnt[0], 1)] = t;
        if (labL[t] == l1 && t != ia1) plist[1][atomicAdd(&pcnt[1], 1)] = t;
    }

    // ---- phase 1: coalesced cooperative dots ----
    // Wave handles its 64 rows in 8 passes. Pass p: 8-lane group g computes row wbase+8p+g;
    // lane class c = l&7 reads float4 chunk c+8i (group reads 128 B contiguous -> 2 lines).
    const int l     = t & 63;
    const int wbase = t & ~63;          // wave's row base
    const int g     = l >> 3;           // row-subgroup within a pass
    const int c     = l & 7;            // f4-chunk class
    const float4* X4 = (const float4*)X;   // row stride = 64 float4

    float4 u[8], w[8];                  // anchor fragments for chunk classes c+8i
    #pragma unroll
    for (int i = 0; i < 8; ++i) {
        u[i] = X4[ia0 * 64 + c + 8 * i];
        w[i] = X4[ia1 * 64 + c + 8 * i];
    }

    float a0 = 0.f, a1 = 0.f, nn = 0.f;     // final dots for row t
    for (int p = 0; p < 8; ++p) {
        const float4* xr = X4 + (size_t)(wbase + p * 8 + g) * 64;
        float pa0 = 0.f, pa1 = 0.f, pnn = 0.f;
        #pragma unroll
        for (int i = 0; i < 8; ++i) {
            const float4 v = xr[c + 8 * i];
            pa0 += u[i].x * v.x + u[i].y * v.y + u[i].z * v.z + u[i].w * v.w;
            pa1 += w[i].x * v.x + w[i].y * v.y + w[i].z * v.z + w[i].w * v.w;
            pnn += v.x * v.x + v.y * v.y + v.z * v.z + v.w * v.w;
        }
        // butterfly within the 8-lane group: all 8 lanes get the row's full dot
        #pragma unroll
        for (int m = 1; m < 8; m <<= 1) {
            pa0 += __shfl_xor(pa0, m, 64);
            pa1 += __shfl_xor(pa1, m, 64);
            pnn += __shfl_xor(pnn, m, 64);
        }
        // wave-transpose gather: thread t's row (wbase+8g+c) was computed in pass p==g
        // by group c; source lane (c<<3)+g.
        const int src = (c << 3) + g;
        const float ga0 = __shfl(pa0, src, 64);
        const float ga1 = __shfl(pa1, src, 64);
        const float gnn = __shfl(pnn, src, 64);
        if (g == p) { a0 = ga0; a1 = ga1; nn = gnn; }
    }

    if (t == ia0) nsh[0] = nn;          // anchor norms from diagonal threads
    if (t == ia1) nsh[1] = nn;
    __syncthreads();

    // ---- distances for column t vs both anchors ----
    float dk0, dk1;
    {
        const float s0 = nsh[0] + nn - 2.0f * a0;
        const float s1 = nsh[1] + nn - 2.0f * a1;
        dk0 = (s0 > 0.0f) ? sqrtf(s0) : 0.0f;
        dk1 = (s1 > 0.0f) ? sqrtf(s1) : 0.0f;
        drowL[0][t] = dk0;
        drowL[1][t] = dk1;
    }
    // pad positive lists to multiple of 8 with sentinel index 512
    if (t < 8) {
        int np = pcnt[0], pad = ((np + 7) & ~7) - np;
        if (t < pad) plist[0][np + t] = 512;
    } else if (t < 16) {
        int q = t - 8;
        int np = pcnt[1], pad = ((np + 7) & ~7) - np;
        if (q < pad) plist[1][np + q] = 512;
    }
    __syncthreads();

    // ---- phase 2: thread owns negative k = t for both anchors ----
    float lsum = 0.0f;
    #pragma unroll
    for (int a = 0; a < 2; ++a) {
        const int li   = labL[ia0 + a];
        const bool neg = (labL[t] != li);
        const float dk = (a == 0) ? dk0 : dk1;
        const int npp  = (pcnt[a] + 7) & ~7;
        float s = 0.0f;
        for (int p = 0; p < npp; p += 8) {
            float dj0 = drowL[a][plist[a][p + 0]];   // uniform -> LDS broadcast
            float dj1 = drowL[a][plist[a][p + 1]];
            float dj2 = drowL[a][plist[a][p + 2]];
            float dj3 = drowL[a][plist[a][p + 3]];
            float dj4 = drowL[a][plist[a][p + 4]];
            float dj5 = drowL[a][plist[a][p + 5]];
            float dj6 = drowL[a][plist[a][p + 6]];
            float dj7 = drowL[a][plist[a][p + 7]];
            s += fmaxf(dj0 - dk + TMARGIN, 0.0f);
            s += fmaxf(dj1 - dk + TMARGIN, 0.0f);
            s += fmaxf(dj2 - dk + TMARGIN, 0.0f);
            s += fmaxf(dj3 - dk + TMARGIN, 0.0f);
            s += fmaxf(dj4 - dk + TMARGIN, 0.0f);
            s += fmaxf(dj5 - dk + TMARGIN, 0.0f);
            s += fmaxf(dj6 - dk + TMARGIN, 0.0f);
            s += fmaxf(dj7 - dk + TMARGIN, 0.0f);
        }
        if (neg) lsum += s;
    }

    // ---- block reduction, write this block's partial to its own slot ----
    #pragma unroll
    for (int o = 32; o > 0; o >>= 1) lsum += __shfl_xor(lsum, o, 64);
    if ((t & 63) == 0) partf[t >> 6] = lsum;
    __syncthreads();
    if (t == 0) {
        float bsum = 0.0f;
        #pragma unroll
        for (int w2 = 0; w2 < 8; ++w2) bsum += partf[w2];
        unsigned int bcnt = 0;
        #pragma unroll
        for (int a = 0; a < 2; ++a) {
            unsigned int np = (unsigned int)pcnt[a];
            bcnt += np * (unsigned int)(BB - 1 - np);
        }
        psum[blockIdx.x]   = bsum;     // plain stores; kernel-boundary coherence
        pcount[blockIdx.x] = bcnt;
    }
}

// ---------------- Kernel 2: reduce 256 partials, finalize ----------------
// 1 block x 256 threads
__global__ void tl_reduce(const float* __restrict__ psum,
                          const unsigned int* __restrict__ pcount,
                          float* __restrict__ out) {
    __shared__ float        sf[4];
    __shared__ unsigned int sc[4];
    const int t = threadIdx.x;
    float        s = psum[t];
    unsigned int c = pcount[t];
    #pragma unroll
    for (int o = 32; o > 0; o >>= 1) {
        s += __shfl_xor(s, o, 64);
        c += __shfl_xor(c, o, 64);
    }
    if ((t & 63) == 0) { sf[t >> 6] = s; sc[t >> 6] = c; }
    __syncthreads();
    if (t == 0) {
        float        tt = sf[0] + sf[1] + sf[2] + sf[3];
        unsigned int cc = sc[0] + sc[1] + sc[2] + sc[3];
        out[0] = (cc > 0u) ? (tt / (float)cc) : 0.0f;
    }
}

extern "C" void kernel_launch(void* const* d_in, const int* in_sizes, int n_in,
                              void* d_out, int out_size, void* d_ws, size_t ws_size,
                              hipStream_t stream) {
    const float* X      = (const float*)d_in[0];   // [512,256] f32
    const int*   labels = (const int*)d_in[1];     // [512] int

    float*        psum   = (float*)d_ws;                          // 256 f32, all rewritten each call
    unsigned int* pcount = (unsigned int*)((char*)d_ws + 1024);   // 256 u32, all rewritten each call

    // NOTE: no hipMemsetAsync — every ws slot consumed is produced this call.
    tl_part<<<NBLK, NTHR, 0, stream>>>(X, labels, psum, pcount);
    tl_reduce<<<1, 256, 0, stream>>>(psum, pcount, (float*)d_out);
}

// Round 8
// 15.883 us; speedup vs baseline: 3.1135x; 1.4569x over previous
//
#include <hip/hip_runtime.h>
#include <math.h>

#define BB 512
#define DD 256
#define TMARGIN 0.2f
#define NBLK 256          // 2 anchors per block
#define NTHR 512          // thread t owns column/negative j = t
#define PSTR 9            // padded LDS stride for partials (gcd(9,32)=1 -> conflict-free reads)

// ---------------- Kernel 1: per-block triplet partials (2 anchors/block) ----------------
// grid 256 x 512. Phase 1: 8-lane-cooperative coalesced row reads; partials transposed
// through padded LDS (no cross-lane shuffles, no divergent gather).
__global__ void __launch_bounds__(NTHR, 2)
tl_part(const float* __restrict__ X,
        const int* __restrict__ labels,
        float* __restrict__ psum,
        unsigned int* __restrict__ pcount) {
    __shared__ float pA[BB * PSTR];     // 18 KB: dot(x_a0, x_row) partials, [row][chunk-class]
    __shared__ float pBt[BB * PSTR];    // 18 KB: dot(x_a1, x_row) partials
    __shared__ float pN[BB * PSTR];     // 18 KB: ||x_row||^2 partials
    __shared__ float drowL[2][520];     // [anchor][col]; slots 512.. = -1e30 sentinel
    __shared__ int   labL[BB];
    __shared__ int   plist[2][520];
    __shared__ int   pcnt[2];
    __shared__ float nsh[2];            // anchor squared norms
    __shared__ float partf[8];

    const int t   = threadIdx.x;        // 0..511 == row/column j it owns
    const int ia0 = blockIdx.x * 2;
    const int ia1 = ia0 + 1;

    labL[t] = labels[t];
    if (t < 2) pcnt[t] = 0;
    if (t < 16) drowL[t >> 3][512 + (t & 7)] = -1e30f;   // sentinel pads
    __syncthreads();

    // ---- build positive lists (LDS atomics; complete by the barrier after phase 1) ----
    {
        const int l0 = labL[ia0], l1 = labL[ia1];
        if (labL[t] == l0 && t != ia0) plist[0][atomicAdd(&pcnt[0], 1)] = t;
        if (labL[t] == l1 && t != ia1) plist[1][atomicAdd(&pcnt[1], 1)] = t;
    }

    // ---- phase 1: coalesced cooperative dots, partials via LDS transpose ----
    // Pass p: 8-lane group g computes row wbase+8p+g; lane class c reads f4 chunks c+8i
    // (group reads 128 B contiguous). Partial sums land in LDS[row][c], stride 9.
    const int l     = t & 63;
    const int wbase = t & ~63;          // wave's 64-row base
    const int g     = l >> 3;           // row-subgroup within a pass
    const int c     = l & 7;            // f4-chunk class
    const float4* X4 = (const float4*)X;   // row stride = 64 float4

    float4 u[8], w[8];                  // anchor fragments for chunk classes c+8i
    #pragma unroll
    for (int i = 0; i < 8; ++i) {
        u[i] = X4[ia0 * 64 + c + 8 * i];
        w[i] = X4[ia1 * 64 + c + 8 * i];
    }

    #pragma unroll
    for (int p = 0; p < 8; ++p) {
        const int row = wbase + p * 8 + g;
        const float4* xr = X4 + (size_t)row * 64;
        float pa0 = 0.f, pa1 = 0.f, pnn = 0.f;
        #pragma unroll
        for (int i = 0; i < 8; ++i) {
            const float4 v = xr[c + 8 * i];
            pa0 += u[i].x * v.x + u[i].y * v.y + u[i].z * v.z + u[i].w * v.w;
            pa1 += w[i].x * v.x + w[i].y * v.y + w[i].z * v.z + w[i].w * v.w;
            pnn += v.x * v.x + v.y * v.y + v.z * v.z + v.w * v.w;
        }
        pA [row * PSTR + c] = pa0;      // wave-internal: written & read by this wave only
        pBt[row * PSTR + c] = pa1;
        pN [row * PSTR + c] = pnn;
    }

    // gather: thread t sums its row's 8 partials per quantity (conflict-free reads)
    float a0 = 0.f, a1 = 0.f, nn = 0.f;
    #pragma unroll
    for (int k = 0; k < 8; ++k) {
        a0 += pA [t * PSTR + k];
        a1 += pBt[t * PSTR + k];
        nn += pN [t * PSTR + k];
    }

    if (t == ia0) nsh[0] = nn;          // anchor norms from diagonal threads
    if (t == ia1) nsh[1] = nn;
    __syncthreads();

    // ---- distances for column t vs both anchors ----
    float dk0, dk1;
    {
        const float s0 = nsh[0] + nn - 2.0f * a0;
        const float s1 = nsh[1] + nn - 2.0f * a1;
        dk0 = (s0 > 0.0f) ? sqrtf(s0) : 0.0f;
        dk1 = (s1 > 0.0f) ? sqrtf(s1) : 0.0f;
        drowL[0][t] = dk0;
        drowL[1][t] = dk1;
    }
    // pad positive lists to multiple of 8 with sentinel index 512
    if (t < 8) {
        int np = pcnt[0], pad = ((np + 7) & ~7) - np;
        if (t < pad) plist[0][np + t] = 512;
    } else if (t < 16) {
        int q = t - 8;
        int np = pcnt[1], pad = ((np + 7) & ~7) - np;
        if (q < pad) plist[1][np + q] = 512;
    }
    __syncthreads();

    // ---- phase 2: thread owns negative k = t for both anchors ----
    float lsum = 0.0f;
    #pragma unroll
    for (int a = 0; a < 2; ++a) {
        const int li   = labL[ia0 + a];
        const bool neg = (labL[t] != li);
        const float dk = (a == 0) ? dk0 : dk1;
        const int npp  = (pcnt[a] + 7) & ~7;
        float s = 0.0f;
        for (int p = 0; p < npp; p += 8) {
            float dj0 = drowL[a][plist[a][p + 0]];   // uniform -> LDS broadcast
            float dj1 = drowL[a][plist[a][p + 1]];
            float dj2 = drowL[a][plist[a][p + 2]];
            float dj3 = drowL[a][plist[a][p + 3]];
            float dj4 = drowL[a][plist[a][p + 4]];
            float dj5 = drowL[a][plist[a][p + 5]];
            float dj6 = drowL[a][plist[a][p + 6]];
            float dj7 = drowL[a][plist[a][p + 7]];
            s += fmaxf(dj0 - dk + TMARGIN, 0.0f);
            s += fmaxf(dj1 - dk + TMARGIN, 0.0f);
            s += fmaxf(dj2 - dk + TMARGIN, 0.0f);
            s += fmaxf(dj3 - dk + TMARGIN, 0.0f);
            s += fmaxf(dj4 - dk + TMARGIN, 0.0f);
            s += fmaxf(dj5 - dk + TMARGIN, 0.0f);
            s += fmaxf(dj6 - dk + TMARGIN, 0.0f);
            s += fmaxf(dj7 - dk + TMARGIN, 0.0f);
        }
        if (neg) lsum += s;
    }

    // ---- block reduction, write this block's partial to its own slot ----
    #pragma unroll
    for (int o = 32; o > 0; o >>= 1) lsum += __shfl_xor(lsum, o, 64);
    if ((t & 63) == 0) partf[t >> 6] = lsum;
    __syncthreads();
    if (t == 0) {
        float bsum = 0.0f;
        #pragma unroll
        for (int w2 = 0; w2 < 8; ++w2) bsum += partf[w2];
        unsigned int bcnt = 0;
        #pragma unroll
        for (int a = 0; a < 2; ++a) {
            unsigned int np = (unsigned int)pcnt[a];
            bcnt += np * (unsigned int)(BB - 1 - np);
        }
        psum[blockIdx.x]   = bsum;     // plain stores; kernel-boundary coherence
        pcount[blockIdx.x] = bcnt;
    }
}

// ---------------- Kernel 2: reduce 256 partials, finalize ----------------
// 1 block x 256 threads
__global__ void tl_reduce(const float* __restrict__ psum,
                          const unsigned int* __restrict__ pcount,
                          float* __restrict__ out) {
    __shared__ float        sf[4];
    __shared__ unsigned int sc[4];
    const int t = threadIdx.x;
    float        s = psum[t];
    unsigned int c = pcount[t];
    #pragma unroll
    for (int o = 32; o > 0; o >>= 1) {
        s += __shfl_xor(s, o, 64);
        c += __shfl_xor(c, o, 64);
    }
    if ((t & 63) == 0) { sf[t >> 6] = s; sc[t >> 6] = c; }
    __syncthreads();
    if (t == 0) {
        float        tt = sf[0] + sf[1] + sf[2] + sf[3];
        unsigned int cc = sc[0] + sc[1] + sc[2] + sc[3];
        out[0] = (cc > 0u) ? (tt / (float)cc) : 0.0f;
    }
}

extern "C" void kernel_launch(void* const* d_in, const int* in_sizes, int n_in,
                              void* d_out, int out_size, void* d_ws, size_t ws_size,
                              hipStream_t stream) {
    const float* X      = (const float*)d_in[0];   // [512,256] f32
    const int*   labels = (const int*)d_in[1];     // [512] int

    float*        psum   = (float*)d_ws;                          // 256 f32, all rewritten each call
    unsigned int* pcount = (unsigned int*)((char*)d_ws + 1024);   // 256 u32, all rewritten each call

    // NOTE: no hipMemsetAsync — fill nodes cost ~13 us in graph replay (round 4->5).
    tl_part<<<NBLK, NTHR, 0, stream>>>(X, labels, psum, pcount);
    tl_reduce<<<1, 256, 0, stream>>>(psum, pcount, (float*)d_out);
}